// Round 1
// baseline (1372.343 us; speedup 1.0000x reference)
//
#include <hip/hip_runtime.h>
#include <stdint.h>

#define N_ROWS 32768
#define K_CB   8192
#define D_DIM  512
#define TAU    0.07f
#define BM     128
#define BK     32
#define NKT    256

typedef __attribute__((ext_vector_type(8))) short bf16x8;
typedef __attribute__((ext_vector_type(16))) float f32x16;

__device__ __forceinline__ unsigned short f2bf(float f) {
    unsigned u = __builtin_bit_cast(unsigned, f);
    u += 0x7FFFu + ((u >> 16) & 1u);          // round-to-nearest-even
    return (unsigned short)(u >> 16);
}

__device__ __forceinline__ void glds16(const unsigned short* g, unsigned short* l) {
    __builtin_amdgcn_global_load_lds(
        (const __attribute__((address_space(1))) unsigned int*)g,
        (__attribute__((address_space(3))) unsigned int*)l, 16, 0, 0);
}

__device__ __forceinline__ unsigned cvtpk(float a, float b) {
    unsigned r;
    asm("v_cvt_pk_bf16_f32 %0, %1, %2" : "=v"(r) : "v"(a), "v"(b));
    return r;
}

// swaps a's lanes 32-63 with b's lanes 0-31 (gfx950)
__device__ __forceinline__ void pl32swap(unsigned& a, unsigned& b) {
    asm volatile("v_permlane32_swap_b32 %0, %1" : "+v"(a), "+v"(b));
}

__device__ __forceinline__ f32x16 zero16() {
    f32x16 z;
    #pragma unroll
    for (int i = 0; i < 16; ++i) z[i] = 0.f;
    return z;
}

// codebook fp32 [K][512] -> two pre-swizzled bf16 arrays of 16B chunks per 32-row tile:
//  rm_sw: chunk c = cbl*64 + (dc ^ (cbl&7))        holds C[tile cb=cbl][d = dc*8 .. +7]
//  t_sw : chunk c = (d*4 + cbc) ^ ((d>>1)&7)       holds C[tile cb=cbc*8+e][d], e=0..7
__global__ __launch_bounds__(512) void prep_codebook(const float* __restrict__ cb,
                                                     unsigned short* __restrict__ rm_sw,
                                                     unsigned short* __restrict__ t_sw) {
    __shared__ unsigned short tile[32 * 512];     // row-major [cbl][d]
    const int j = blockIdx.x, t = threadIdx.x;
    const float2* src = (const float2*)(cb + (size_t)j * (BK * D_DIM));
    unsigned* t32 = (unsigned*)tile;
    #pragma unroll
    for (int it = 0; it < 16; ++it) {
        int e2 = it * 512 + t;
        float2 v = src[e2];
        t32[e2] = (unsigned)f2bf(v.x) | ((unsigned)f2bf(v.y) << 16);
    }
    __syncthreads();
    uint4* rmd = (uint4*)rm_sw + (size_t)j * 2048;
    uint4* twd = (uint4*)t_sw + (size_t)j * 2048;
    #pragma unroll
    for (int it = 0; it < 4; ++it) {
        int L = it * 512 + t;
        int cbl = L >> 6, dc = L & 63;
        int c = cbl * 64 + (dc ^ (cbl & 7));
        rmd[c] = *(const uint4*)&tile[cbl * 512 + dc * 8];
    }
    #pragma unroll
    for (int it = 0; it < 4; ++it) {
        int M = it * 512 + t;
        int d = M >> 2, cbc = M & 3;
        int c = (d * 4 + cbc) ^ ((d >> 1) & 7);
        unsigned short tmp[8];
        #pragma unroll
        for (int e = 0; e < 8; ++e) tmp[e] = tile[(cbc * 8 + e) * 512 + d];
        twd[c] = *(const uint4*)tmp;
    }
}

// 32x32x16 restructure: 4 wave-pairs x 32 rows; pair splits K=512 for QK (kh = d-half),
// S-partials exchanged via LDS; P transposed in-register (cvt_pk_bf16 + permlane32_swap);
// PV splits d by kh, k-step kh uses own P-frag (pre-barrier), k-step kh^1 uses partner's.
__global__ __launch_bounds__(512, 2) void cbmap_main(const float* __restrict__ x,
                                                     const unsigned short* __restrict__ rm_sw,
                                                     const unsigned short* __restrict__ t_sw,
                                                     float* __restrict__ out) {
    __shared__ unsigned short s_rm[2][16384];   // 2 x 32 KB, cb-major swizzled tile
    __shared__ unsigned short s_ct[2][16384];   // 2 x 32 KB, d-major swizzled tile
    __shared__ float s_sx[8][512];              // 8 x 2 KB, S-partial exchange (2-way max)
    __shared__ unsigned s_px[8][256];           // 8 x 1 KB, P-fragment exchange (conflict-free)
    __shared__ float s_red[8][32];              // norm (prologue) / denom (epilogue)

    const int tid = threadIdx.x;
    const int w = tid >> 6, lane = tid & 63;
    const int lo5 = lane & 31, hi = lane >> 5;
    const int pr = w >> 1, kh = w & 1;
    const int srow0 = blockIdx.x * BM + pr * 32;  // pair's 32 S-rows
    const int swz = lo5 & 7;

    // ---- prologue: each wave loads 32 rows x its 256-d half; L2-norm; fold 1/TAU
    const float* xrow = x + (size_t)(srow0 + lo5) * D_DIM + kh * 256 + hi * 8;
    float4 va[16], vb[16];
    float ss = 0.f;
    #pragma unroll
    for (int ks = 0; ks < 16; ++ks) {
        va[ks] = *(const float4*)(xrow + ks * 16);
        vb[ks] = *(const float4*)(xrow + ks * 16 + 4);
        ss += va[ks].x * va[ks].x + va[ks].y * va[ks].y + va[ks].z * va[ks].z + va[ks].w * va[ks].w;
        ss += vb[ks].x * vb[ks].x + vb[ks].y * vb[ks].y + vb[ks].z * vb[ks].z + vb[ks].w * vb[ks].w;
    }
    ss += __shfl_xor(ss, 32, 64);               // lane pair (l, l+32) -> wave half-sum per row

    // preload tile 0 -> buffer 0
    #pragma unroll
    for (int k = 0; k < 4; ++k) {
        glds16(rm_sw + (size_t)(k * 512 + tid) * 8, &s_rm[0][(k * 512 + tid) * 8]);
        glds16(t_sw  + (size_t)(k * 512 + tid) * 8, &s_ct[0][(k * 512 + tid) * 8]);
    }
    if (lane < 32) s_red[w][lo5] = ss;
    __syncthreads();                             // norm partials visible + preload drained
    const float tot = ss + s_red[w ^ 1][lo5];
    const float scale = 1.0f / (fmaxf(sqrtf(tot), 1e-12f) * TAU);

    bf16x8 afrag[16];                            // B-frags: x[row lo5][kh*256 + ks*16 + hi*8 + e]
    #pragma unroll
    for (int ks = 0; ks < 16; ++ks) {
        bf16x8 f;
        f[0] = (short)f2bf(va[ks].x * scale); f[1] = (short)f2bf(va[ks].y * scale);
        f[2] = (short)f2bf(va[ks].z * scale); f[3] = (short)f2bf(va[ks].w * scale);
        f[4] = (short)f2bf(vb[ks].x * scale); f[5] = (short)f2bf(vb[ks].y * scale);
        f[6] = (short)f2bf(vb[ks].z * scale); f[7] = (short)f2bf(vb[ks].w * scale);
        afrag[ks] = f;
    }

    f32x16 acc[8];                               // O[32 rows x (kh*256 .. +255)]
    #pragma unroll
    for (int i = 0; i < 8; ++i) acc[i] = zero16();
    float dsum = 0.f;

    for (int j = 0; j < NKT; ++j) {
        const int p = j & 1;
        const size_t nb = (size_t)((j + 1) & (NKT - 1)) * 16384;
        #pragma unroll
        for (int k = 0; k < 4; ++k) {
            glds16(rm_sw + nb + (size_t)(k * 512 + tid) * 8, &s_rm[p ^ 1][(k * 512 + tid) * 8]);
            glds16(t_sw  + nb + (size_t)(k * 512 + tid) * 8, &s_ct[p ^ 1][(k * 512 + tid) * 8]);
        }

        // ---- S_part^T[32cb x 32row] over this wave's d-half (A = C-frag LDS, B = x regs)
        const unsigned short* srm = s_rm[p] + (size_t)lo5 * 512 + (size_t)kh * 256;
        f32x16 sacc = zero16();
        #pragma unroll
        for (int ks = 0; ks < 16; ++ks) {
            bf16x8 cf = *(const bf16x8*)&srm[((ks * 2 + hi) ^ swz) * 8];
            sacc = __builtin_amdgcn_mfma_f32_32x32x16_bf16(cf, afrag[ks], sacc, 0, 0, 0);
        }

        // ---- give partner its kept 8 regs (it keeps regs kh^1 * 8 ..)
        float* sxw = &s_sx[w][lane * 8];
        if (kh == 0) {
            *(float4*)sxw       = (float4){sacc[8],  sacc[9],  sacc[10], sacc[11]};
            *(float4*)(sxw + 4) = (float4){sacc[12], sacc[13], sacc[14], sacc[15]};
        } else {
            *(float4*)sxw       = (float4){sacc[0], sacc[1], sacc[2], sacc[3]};
            *(float4*)(sxw + 4) = (float4){sacc[4], sacc[5], sacc[6], sacc[7]};
        }
        __syncthreads();                         // B1: S-partials visible (+ prefetch drained)

        const float* sxr = &s_sx[w ^ 1][lane * 8];
        const float4 rlo = *(const float4*)sxr;
        const float4 rhi = *(const float4*)(sxr + 4);
        float e0, e1, e2, e3, e4, e5, e6, e7;
        if (kh == 0) {
            e0 = sacc[0] + rlo.x; e1 = sacc[1] + rlo.y; e2 = sacc[2] + rlo.z; e3 = sacc[3] + rlo.w;
            e4 = sacc[4] + rhi.x; e5 = sacc[5] + rhi.y; e6 = sacc[6] + rhi.z; e7 = sacc[7] + rhi.w;
        } else {
            e0 = sacc[8]  + rlo.x; e1 = sacc[9]  + rlo.y; e2 = sacc[10] + rlo.z; e3 = sacc[11] + rlo.w;
            e4 = sacc[12] + rhi.x; e5 = sacc[13] + rhi.y; e6 = sacc[14] + rhi.z; e7 = sacc[15] + rhi.w;
        }
        const float p0 = __expf(e0), p1 = __expf(e1), p2 = __expf(e2), p3 = __expf(e3);
        const float p4 = __expf(e4), p5 = __expf(e5), p6 = __expf(e6), p7 = __expf(e7);
        dsum += ((p0 + p1) + (p2 + p3)) + ((p4 + p5) + (p6 + p7));

        // in-register transpose to PV A-frag layout: lane needs P[row lo5][cb hi*8 + e]
        unsigned q0 = cvtpk(p0, p1), q1 = cvtpk(p2, p3);
        unsigned q2 = cvtpk(p4, p5), q3 = cvtpk(p6, p7);
        pl32swap(q0, q2);
        pl32swap(q1, q3);
        uint4 mo; mo.x = q0; mo.y = q1; mo.z = q2; mo.w = q3;
        *(uint4*)&s_px[w][lane * 4] = mo;
        const bf16x8 pa_own = __builtin_bit_cast(bf16x8, mo);   // k-step = kh

        // ---- PV half 1 (k-step kh) with own P-frag, overlapped before the barrier
        const unsigned short* sct = s_ct[p];
        const int dbase = kh * 256 + lo5;
        const int cb_own = kh * 2 + hi, cb_oth = (kh ^ 1) * 2 + hi;
        #pragma unroll
        for (int dt = 0; dt < 8; ++dt) {
            const int d = dbase + dt * 32;
            const int dsw = (d >> 1) & 7;
            bf16x8 bo = *(const bf16x8*)&sct[((d * 4 + cb_own) ^ dsw) * 8];
            acc[dt] = __builtin_amdgcn_mfma_f32_32x32x16_bf16(pa_own, bo, acc[dt], 0, 0, 0);
        }
        __syncthreads();                         // B2: partner P-frag visible

        const uint4 po = *(const uint4*)&s_px[w ^ 1][lane * 4];
        const bf16x8 pa_oth = __builtin_bit_cast(bf16x8, po);   // k-step = kh^1
        #pragma unroll
        for (int dt = 0; dt < 8; ++dt) {
            const int d = dbase + dt * 32;
            const int dsw = (d >> 1) & 7;
            bf16x8 bo = *(const bf16x8*)&sct[((d * 4 + cb_oth) ^ dsw) * 8];
            acc[dt] = __builtin_amdgcn_mfma_f32_32x32x16_bf16(pa_oth, bo, acc[dt], 0, 0, 0);
        }
        __syncthreads();                         // B3: buffer-p reads done before next overwrite
    }

    // ---- epilogue: combine denominators across lane halves and wave pair, divide, store
    dsum += __shfl_xor(dsum, 32, 64);
    if (lane < 32) s_red[w][lo5] = dsum;
    __syncthreads();
    float inv[16];
    #pragma unroll
    for (int r = 0; r < 16; ++r) {
        const int row = (r & 3) + 8 * (r >> 2) + 4 * hi;
        inv[r] = 1.0f / (s_red[2 * pr][row] + s_red[2 * pr + 1][row]);
    }
    float* ob = out + (size_t)srow0 * D_DIM + kh * 256 + lo5;
    #pragma unroll
    for (int dt = 0; dt < 8; ++dt) {
        #pragma unroll
        for (int r = 0; r < 16; ++r) {
            const int row = (r & 3) + 8 * (r >> 2) + 4 * hi;
            ob[(size_t)row * D_DIM + dt * 32] = acc[dt][r] * inv[r];
        }
    }
}

extern "C" void kernel_launch(void* const* d_in, const int* in_sizes, int n_in,
                              void* d_out, int out_size, void* d_ws, size_t ws_size,
                              hipStream_t stream) {
    const float* x  = (const float*)d_in[0];
    const float* cb = (const float*)d_in[1];
    unsigned short* rm_sw = (unsigned short*)d_ws;                       // 8 MB
    unsigned short* t_sw  = rm_sw + (size_t)K_CB * D_DIM;                // 8 MB
    float* outp = (float*)d_out;

    prep_codebook<<<NKT, 512, 0, stream>>>(cb, rm_sw, t_sw);
    cbmap_main<<<N_ROWS / BM, 512, 0, stream>>>(x, rm_sw, t_sw, outp);
}